// Round 2
// baseline (222.861 us; speedup 1.0000x reference)
//
#include <hip/hip_runtime.h>

// out[m,k] = D*(w-1)*rowsum(t[m]) broadcast over k (K = D = 2048).
//
// R1-R8: all fused variants 71-82 us. R9 (2-kernel split, pure read kernel +
// pure write kernel): only -2 us harness => split kernels totalled ~59 us,
// NOT the 41 us pure-stream floor. So stream purity per-kernel is not
// sufficient; suspects are the extra graph-node gap and wave churn (16384
// 8-load waves + 64 KB rs round-trip).
//
// R10: ONE kernel, phase-separated in TIME, whole grid co-resident.
//   - 8 rows (64 KB) per wave; grid = 512 blocks = 2048 waves = 8 waves/CU,
//     ALL resident simultaneously (~95 VGPR < 128 => 16-wave/CU capacity).
//     No generations => device-wide read phase, then device-wide write phase.
//     (R0's fused kernel launched 4096 waves at ~12/CU residency: later
//     generations' reads overlapped earlier generations' writes.)
//   - Read phase: 2-row double-buffered NT loads (16 KB in flight/wave,
//     128 KB/CU >> ~10 KB Little's-law requirement), butterfly-reduce each
//     row into 8 register sums. No stores issued anywhere in this phase.
//   - __syncthreads(), then pure write phase: 8 rows x 8 NT dwordx4 stores.
// Single dispatch: no inter-kernel gap, no rs round-trip.

#define M_ROWS 16384
#define D_COLS 2048
#define F4_PER_ROW (D_COLS / 4)   // 512
#define WAVES_PER_BLOCK 4
#define BLOCK_SIZE (WAVES_PER_BLOCK * 64)
#define ROWS_PER_WAVE 8
#define GRID_BLOCKS (M_ROWS / (WAVES_PER_BLOCK * ROWS_PER_WAVE))  // 512

typedef float vf4 __attribute__((ext_vector_type(4)));

__global__ __launch_bounds__(BLOCK_SIZE)
void perm_equiv_phased(const float* __restrict__ t,
                       const float* __restrict__ w,
                       float* __restrict__ out) {
    const int lane  = threadIdx.x & 63;
    const int gwave = blockIdx.x * WAVES_PER_BLOCK + (threadIdx.x >> 6);
    const size_t row0 = (size_t)gwave * ROWS_PER_WAVE;   // 8 contiguous rows

    const float scale = (float)D_COLS * (w[0] - 1.0f);

    const vf4* base = reinterpret_cast<const vf4*>(t) + row0 * F4_PER_ROW;

    vf4 buf0[8], buf1[8];          // 2-row double buffer (64 VGPRs)
    float sums[ROWS_PER_WAVE];     // fully unrolled -> registers

    // ---- pure READ phase ----
    #pragma unroll
    for (int j = 0; j < 8; ++j)
        buf0[j] = __builtin_nontemporal_load(base + j * 64 + lane);

    #pragma unroll
    for (int r = 0; r < ROWS_PER_WAVE; ++r) {
        // issue next row's loads before consuming this row (keeps 16 KB in flight)
        if (r + 1 < ROWS_PER_WAVE) {
            const vf4* p = base + (size_t)(r + 1) * F4_PER_ROW;
            if (r & 1) {
                #pragma unroll
                for (int j = 0; j < 8; ++j)
                    buf0[j] = __builtin_nontemporal_load(p + j * 64 + lane);
            } else {
                #pragma unroll
                for (int j = 0; j < 8; ++j)
                    buf1[j] = __builtin_nontemporal_load(p + j * 64 + lane);
            }
        }

        float s = 0.0f;
        if (r & 1) {
            #pragma unroll
            for (int j = 0; j < 8; ++j)
                s += (buf1[j].x + buf1[j].y) + (buf1[j].z + buf1[j].w);
        } else {
            #pragma unroll
            for (int j = 0; j < 8; ++j)
                s += (buf0[j].x + buf0[j].y) + (buf0[j].z + buf0[j].w);
        }

        // wave-64 butterfly: every lane ends with the full row sum.
        #pragma unroll
        for (int m = 32; m > 0; m >>= 1)
            s += __shfl_xor(s, m, 64);

        sums[r] = scale * s;
    }

    __syncthreads();   // sharpen the phase boundary within the block

    // ---- pure WRITE phase ----
    vf4* obase = reinterpret_cast<vf4*>(out) + row0 * F4_PER_ROW;
    #pragma unroll
    for (int r = 0; r < ROWS_PER_WAVE; ++r) {
        vf4 v4;
        v4.x = sums[r]; v4.y = sums[r]; v4.z = sums[r]; v4.w = sums[r];
        vf4* orow = obase + (size_t)r * F4_PER_ROW;
        #pragma unroll
        for (int j = 0; j < 8; ++j)
            __builtin_nontemporal_store(v4, orow + j * 64 + lane);
    }
}

extern "C" void kernel_launch(void* const* d_in, const int* in_sizes, int n_in,
                              void* d_out, int out_size, void* d_ws, size_t ws_size,
                              hipStream_t stream) {
    const float* t = (const float*)d_in[0];
    const float* w = (const float*)d_in[1];
    float* out = (float*)d_out;
    perm_equiv_phased<<<GRID_BLOCKS, BLOCK_SIZE, 0, stream>>>(t, w, out);
}